// Round 1
// baseline (1210.227 us; speedup 1.0000x reference)
//
#include <hip/hip_runtime.h>
#include <hip/hip_bf16.h>

// CATSCluster: fused 3-stream MLP (768->256->128) + combine on MI355X.
// Strategy: split-precision bf16 MFMA (x=hi+lo, W=hi+lo; keep hh+hl+lh terms)
// for GEMM1; H rounded to single bf16; W2/W4 split (2 terms) for GEMM2;
// final combine/dot/tanh in fp32.

typedef short short8 __attribute__((ext_vector_type(8)));   // 8 x bf16 (4 VGPRs)
typedef float f32x4 __attribute__((ext_vector_type(4)));    // MFMA accumulator

// d_ws layout (in unsigned short elements)
#define W1H_OFF 0u
#define W1L_OFF 196608u
#define W3H_OFF 393216u
#define W3L_OFF 589824u
#define W2H_OFF 786432u
#define W2L_OFF 819200u
#define W4H_OFF 851968u
#define W4L_OFF 884736u
// total: 917504 shorts = 1,835,008 bytes of d_ws

__device__ __forceinline__ unsigned short bf16_rne(float f) {
  unsigned int u = __float_as_uint(f);
  u += 0x7FFFu + ((u >> 16) & 1u);      // round-to-nearest-even
  return (unsigned short)(u >> 16);
}

__device__ __forceinline__ void split_bf16(float f, unsigned short& h, unsigned short& l) {
  h = bf16_rne(f);
  float fh = __uint_as_float(((unsigned int)h) << 16);
  l = bf16_rne(f - fh);                 // residual; |x - hi - lo| ~ 2^-18 |x|
}

__global__ __launch_bounds__(256) void prep_weights(
    const float* __restrict__ W1, const float* __restrict__ W2,
    const float* __restrict__ W3, const float* __restrict__ W4,
    unsigned short* __restrict__ ws)
{
  int i = blockIdx.x * 256 + threadIdx.x;
  if (i < 196608) {
    unsigned short h, l;
    split_bf16(W1[i], h, l); ws[W1H_OFF + i] = h; ws[W1L_OFF + i] = l;
    split_bf16(W3[i], h, l); ws[W3H_OFF + i] = h; ws[W3L_OFF + i] = l;
    if (i < 32768) {
      split_bf16(W2[i], h, l); ws[W2H_OFF + i] = h; ws[W2L_OFF + i] = l;
      split_bf16(W4[i], h, l); ws[W4H_OFF + i] = h; ws[W4L_OFF + i] = l;
    }
  }
}

#define STRIDE_A 40    // shorts per A-row in LDS (32 used; 80B stride -> 16B aligned, 2-way banks = free)
#define STRIDE_H 264   // shorts per H-row in LDS (256 used; 528B stride -> 16B aligned, 2-way banks = free)

__global__ __launch_bounds__(256) void catsc_main(
    const float* __restrict__ X, const unsigned short* __restrict__ ws,
    const float* __restrict__ W5, float* __restrict__ out)
{
  __shared__ short lsA[2][2][64 * STRIDE_A];  // [dbuf][hi/lo][row*40+k]  20,480 B
  __shared__ short lsH[64 * STRIDE_H];        // relu(h) as bf16          33,792 B
  __shared__ float lsPart[4][64];             // cross-wave dot partials   1,024 B

  const int tid  = threadIdx.x;
  const int wave = tid >> 6;
  const int lane = tid & 63;
  const int l15  = lane & 15;
  const int q    = lane >> 4;     // quad index 0..3
  const int blk  = blockIdx.x;    // 0..1023, 64 rows each; 64 blocks per n (4096/64)

  // X_data is (16, 4097, 2304); skip row 0 of each n.
  const float* Xb = X + (size_t)((blk >> 6) * 4097 + 1 + ((blk & 63) << 6)) * 2304;

  // cooperative staging coords: thread -> (row, 4-float segment)
  const int srow = tid >> 3;        // 0..31 (+32 on second iter)
  const int f4   = (tid & 7) << 2;  // float offset 0,4,...,28 within 32-col chunk

  f32x4 z[3][4][2];                 // relu(GEMM2) per stream, C-layout regs

#pragma unroll
  for (int s = 0; s < 3; ++s) {
    const unsigned short* B1h = ws + (s == 0 ? W3H_OFF : W1H_OFF);
    const unsigned short* B1l = ws + (s == 0 ? W3L_OFF : W1L_OFF);
    const unsigned short* B2h = ws + (s == 0 ? W4H_OFF : W2H_OFF);
    const unsigned short* B2l = ws + (s == 0 ? W4L_OFF : W2L_OFF);
    const int so = s * 768;         // column offset: q=0, p1=768, p2=1536

    f32x4 acc[4][4];
#pragma unroll
    for (int m = 0; m < 4; ++m)
#pragma unroll
      for (int n = 0; n < 4; ++n)
        acc[m][n] = f32x4{0.f, 0.f, 0.f, 0.f};

    // ---- stage chunk 0 into buf 0 ----
#pragma unroll
    for (int it = 0; it < 2; ++it) {
      int rr = srow + 32 * it;
      float4 v = *(const float4*)(Xb + (size_t)rr * 2304 + so + f4);
      unsigned short h0,h1,h2,h3,l0,l1,l2,l3;
      split_bf16(v.x,h0,l0); split_bf16(v.y,h1,l1);
      split_bf16(v.z,h2,l2); split_bf16(v.w,h3,l3);
      uint2 ph, pl;
      ph.x = (unsigned)h0 | ((unsigned)h1 << 16); ph.y = (unsigned)h2 | ((unsigned)h3 << 16);
      pl.x = (unsigned)l0 | ((unsigned)l1 << 16); pl.y = (unsigned)l2 | ((unsigned)l3 << 16);
      *(uint2*)&lsA[0][0][rr * STRIDE_A + f4] = ph;
      *(uint2*)&lsA[0][1][rr * STRIDE_A + f4] = pl;
    }
    __syncthreads();

    // ---- GEMM1 K-loop: 24 chunks of K=32, double-buffered ----
    for (int c = 0; c < 24; ++c) {
      const int b = c & 1;
      if (c + 1 < 24) {
        const int nb = b ^ 1;
#pragma unroll
        for (int it = 0; it < 2; ++it) {
          int rr = srow + 32 * it;
          float4 v = *(const float4*)(Xb + (size_t)rr * 2304 + so + (c + 1) * 32 + f4);
          unsigned short h0,h1,h2,h3,l0,l1,l2,l3;
          split_bf16(v.x,h0,l0); split_bf16(v.y,h1,l1);
          split_bf16(v.z,h2,l2); split_bf16(v.w,h3,l3);
          uint2 ph, pl;
          ph.x = (unsigned)h0 | ((unsigned)h1 << 16); ph.y = (unsigned)h2 | ((unsigned)h3 << 16);
          pl.x = (unsigned)l0 | ((unsigned)l1 << 16); pl.y = (unsigned)l2 | ((unsigned)l3 << 16);
          *(uint2*)&lsA[nb][0][rr * STRIDE_A + f4] = ph;
          *(uint2*)&lsA[nb][1][rr * STRIDE_A + f4] = pl;
        }
      }
      // B fragments (weights, bf16 hi/lo) straight from global/L2.
      // B-operand layout: lane needs W[n = nt*16 + l15][k = c*32 + q*8 + j]
      short8 Bh[4], Bl[4];
#pragma unroll
      for (int n = 0; n < 4; ++n) {
        size_t off = (size_t)((wave * 4 + n) * 16 + l15) * 768 + c * 32 + q * 8;
        Bh[n] = *(const short8*)(B1h + off);
        Bl[n] = *(const short8*)(B1l + off);
      }
      // A fragments from LDS: A[m = mt*16 + l15][k = q*8 + j]
      short8 Ah[4], Al[4];
#pragma unroll
      for (int m = 0; m < 4; ++m) {
        int a = (m * 16 + l15) * STRIDE_A + q * 8;
        Ah[m] = *(const short8*)&lsA[b][0][a];
        Al[m] = *(const short8*)&lsA[b][1][a];
      }
      // 3-term split product; term-major order keeps same-acc MFMAs 16 apart
#pragma unroll
      for (int m = 0; m < 4; ++m)
#pragma unroll
        for (int n = 0; n < 4; ++n)
          acc[m][n] = __builtin_amdgcn_mfma_f32_16x16x32_bf16(Ah[m], Bh[n], acc[m][n], 0, 0, 0);
#pragma unroll
      for (int m = 0; m < 4; ++m)
#pragma unroll
        for (int n = 0; n < 4; ++n)
          acc[m][n] = __builtin_amdgcn_mfma_f32_16x16x32_bf16(Ah[m], Bl[n], acc[m][n], 0, 0, 0);
#pragma unroll
      for (int m = 0; m < 4; ++m)
#pragma unroll
        for (int n = 0; n < 4; ++n)
          acc[m][n] = __builtin_amdgcn_mfma_f32_16x16x32_bf16(Al[m], Bh[n], acc[m][n], 0, 0, 0);
      __syncthreads();
    }

    // ---- H = relu(acc) -> LDS as bf16 (C-layout: col=l15, row=q*4+i) ----
#pragma unroll
    for (int m = 0; m < 4; ++m)
#pragma unroll
      for (int n = 0; n < 4; ++n) {
        int col = (wave * 4 + n) * 16 + l15;
#pragma unroll
        for (int i = 0; i < 4; ++i) {
          int row = m * 16 + q * 4 + i;
          lsH[row * STRIDE_H + col] = bf16_rne(fmaxf(acc[m][n][i], 0.f));
        }
      }
    __syncthreads();

    // ---- GEMM2: (64 x 256) x (256 -> 128), H bf16 x W split (2 terms) ----
    f32x4 acc2[4][2];
#pragma unroll
    for (int m = 0; m < 4; ++m)
#pragma unroll
      for (int n = 0; n < 2; ++n)
        acc2[m][n] = f32x4{0.f, 0.f, 0.f, 0.f};

    for (int c2 = 0; c2 < 8; ++c2) {
      short8 Ch[2], Cl[2];
#pragma unroll
      for (int n2 = 0; n2 < 2; ++n2) {
        size_t off = (size_t)((wave * 2 + n2) * 16 + l15) * 256 + c2 * 32 + q * 8;
        Ch[n2] = *(const short8*)(B2h + off);
        Cl[n2] = *(const short8*)(B2l + off);
      }
      short8 Ha[4];
#pragma unroll
      for (int m = 0; m < 4; ++m)
        Ha[m] = *(const short8*)&lsH[(m * 16 + l15) * STRIDE_H + c2 * 32 + q * 8];
#pragma unroll
      for (int m = 0; m < 4; ++m)
#pragma unroll
        for (int n2 = 0; n2 < 2; ++n2)
          acc2[m][n2] = __builtin_amdgcn_mfma_f32_16x16x32_bf16(Ha[m], Ch[n2], acc2[m][n2], 0, 0, 0);
#pragma unroll
      for (int m = 0; m < 4; ++m)
#pragma unroll
        for (int n2 = 0; n2 < 2; ++n2)
          acc2[m][n2] = __builtin_amdgcn_mfma_f32_16x16x32_bf16(Ha[m], Cl[n2], acc2[m][n2], 0, 0, 0);
    }
#pragma unroll
    for (int m = 0; m < 4; ++m)
#pragma unroll
      for (int n2 = 0; n2 < 2; ++n2)
#pragma unroll
        for (int i = 0; i < 4; ++i)
          z[s][m][n2][i] = fmaxf(acc2[m][n2][i], 0.f);
    // No barrier needed here: lsH(s+1) writes happen after 24 barriers of the
    // next GEMM1 loop; lsA buffers were last read before the final c-loop barrier.
  }

  // ---- combine: out = tanh(relu(sum_o zq * |zp1 - zp2| * W5[o])) ----
  const float w5c0 = W5[(wave * 2 + 0) * 16 + l15];
  const float w5c1 = W5[(wave * 2 + 1) * 16 + l15];
#pragma unroll
  for (int m = 0; m < 4; ++m) {
#pragma unroll
    for (int i = 0; i < 4; ++i) {
      float v = z[0][m][0][i] * fabsf(z[1][m][0][i] - z[2][m][0][i]) * w5c0
              + z[0][m][1][i] * fabsf(z[1][m][1][i] - z[2][m][1][i]) * w5c1;
      // reduce over the 16 cols held by l15 (within each quad group)
      v += __shfl_xor(v, 1);
      v += __shfl_xor(v, 2);
      v += __shfl_xor(v, 4);
      v += __shfl_xor(v, 8);
      if (l15 == 0) lsPart[wave][m * 16 + q * 4 + i] = v;
    }
  }
  __syncthreads();
  if (tid < 64) {
    float sum = lsPart[0][tid] + lsPart[1][tid] + lsPart[2][tid] + lsPart[3][tid];
    out[(size_t)blk * 64 + tid] = tanhf(fmaxf(sum, 0.f));
  }
}

extern "C" void kernel_launch(void* const* d_in, const int* in_sizes, int n_in,
                              void* d_out, int out_size, void* d_ws, size_t ws_size,
                              hipStream_t stream) {
  const float* X  = (const float*)d_in[0];
  const float* W1 = (const float*)d_in[1];
  const float* W2 = (const float*)d_in[2];
  const float* W3 = (const float*)d_in[3];
  const float* W4 = (const float*)d_in[4];
  const float* W5 = (const float*)d_in[5];
  float* out = (float*)d_out;
  unsigned short* ws = (unsigned short*)d_ws;  // needs 1.75 MB

  prep_weights<<<dim3(768), dim3(256), 0, stream>>>(W1, W2, W3, W4, ws);
  catsc_main<<<dim3(1024), dim3(256), 0, stream>>>(X, ws, W5, out);
}